// Round 9
// baseline (10805.392 us; speedup 1.0000x reference)
//
#include <hip/hip_runtime.h>
#include <hip/hip_bf16.h>
#include <math.h>

// ---------------------------------------------------------------------------
// Problem constants
// ---------------------------------------------------------------------------
#define BB   128     // batch
#define TT   1024    // time
#define CC_  512     // channels / variates (N)
#define DD   1024    // model dim
#define DF_  2048    // fc hidden
#define HH   64      // pool hidden
#define INV_SQRT_D 0.03125f   // 1/sqrt(1024)

typedef __bf16 bf16;
typedef __attribute__((ext_vector_type(8))) __bf16 bf16x8;
typedef __attribute__((ext_vector_type(4))) __bf16 bf16x4;
typedef __attribute__((ext_vector_type(2))) __bf16 bf16x2;
typedef __attribute__((ext_vector_type(4))) float f32x4;

__device__ __forceinline__ void gload_lds16(const void* g, void* l) {
    // async global->LDS, 16B per lane; LDS dest = wave-uniform base + lane*16
    __builtin_amdgcn_global_load_lds(
        (const __attribute__((address_space(1))) void*)g,
        (__attribute__((address_space(3))) void*)l, 16, 0, 0);
}

__device__ __forceinline__ void split2(float v, bf16& h, bf16& l) {
    h = (bf16)v; l = (bf16)(v - (float)h);
}

// ---------------------------------------------------------------------------
// Fused split-bf16 MFMA GEMM.  C[m,n] = alpha*sum_k A[m,k]*B[n,k] + add_c + bias[n]
//   A ~ Ah+Al stored [M][K] (lda); B ~ Bh+Bl stored [N][K] (ldb).
//   Single K-sweep; per K-step stages Ah/Al/Bh/Bl tiles (SINGLE-buffered,
//   64 KB LDS -> 2 blocks/CU; cross-block overlap hides the staging drain)
//   and issues AhBh + AlBh + AhBl (Al*Bl dropped, ~2^-16 rel).
//   OUT: 0 = fp32 C[M][N];  1 = bf16 hi/lo C[M][N];  2 = bf16 hi/lo C^T[N][M]
// Tile 256x256, BK=32, 8 waves (512 thr); per-wave output 128x64.
// LDS per tensor: [q=4][row=256][8] bf16 = 16 KB; total 64 KB.
// __launch_bounds__(512,4) caps VGPR at 128 -> 2 blocks resident per CU.
// M,N multiples of 256; K multiple of 32.
// ---------------------------------------------------------------------------
template <int OUT>
__global__ __launch_bounds__(512, 4) void mfma_gemm(
    const bf16* __restrict__ Ah, const bf16* __restrict__ Al,
    const bf16* __restrict__ Bh, const bf16* __restrict__ Bl,
    const float* __restrict__ bias, const float* __restrict__ add_c,
    void* __restrict__ C0, void* __restrict__ C1,
    int M, int N, int K, int lda, int ldb,
    long long sA, long long sB, long long sC, float alpha)
{
    // ---- XCD swizzle on flattened (x,y); identity when nwg % 8 != 0 ----
    const int gx = gridDim.x;
    const int nwg = gx * gridDim.y;
    int lin = blockIdx.y * gx + blockIdx.x;
    if ((nwg & 7) == 0) {
        const int cpx = nwg >> 3;
        lin = (lin & 7) * cpx + (lin >> 3);
    }
    const int bx = lin % gx, by = lin / gx;

    const int bz   = blockIdx.z;
    const int t    = threadIdx.x;
    const int wave = t >> 6, lane = t & 63;
    const int m0 = by * 256, n0 = bx * 256;
    const int wm = (wave >> 2) * 128;      // 2 M-groups of 128
    const int wn = (wave & 3) * 64;        // 4 N-groups of 64

    __shared__ __align__(16) bf16 Ash[8192];   // 16 KB each, 64 KB total
    __shared__ __align__(16) bf16 Asl[8192];
    __shared__ __align__(16) bf16 Bsh[8192];
    __shared__ __align__(16) bf16 Bsl[8192];

    f32x4 acc[8][4] = {};

    // staging: thread t stages 16B units (t) and (t+512) of each 16 KB tile
    //   unit u -> row = u & 255, q-pair = u >> 8;  LDS byte = u*16 (+8192)
    const int srow  = t & 255;
    const int sq8   = (t >> 8) * 8;              // k-offset within tile: 0/8
    const int wbyte = wave * 1024;               // wave-uniform LDS base
    const long long aoff = (long long)bz * sA + (long long)(m0 + srow) * lda + sq8;
    const long long boff = (long long)bz * sB + (long long)(n0 + srow) * ldb + sq8;
    const bf16* pAh = Ah + aoff; const bf16* pAl = Al + aoff;
    const bf16* pBh = Bh + boff; const bf16* pBl = Bl + boff;

    const int q   = lane >> 4;   // k-chunk for fragment reads
    const int r16 = lane & 15;
    const bf16x8* AhV = (const bf16x8*)Ash;
    const bf16x8* AlV = (const bf16x8*)Asl;
    const bf16x8* BhV = (const bf16x8*)Bsh;
    const bf16x8* BlV = (const bf16x8*)Bsl;

    for (int k0 = 0; k0 < K; k0 += 32) {
        __syncthreads();                       // previous compute done
        gload_lds16(pAh + k0,      (char*)Ash + wbyte);
        gload_lds16(pAh + k0 + 16, (char*)Ash + wbyte + 8192);
        gload_lds16(pAl + k0,      (char*)Asl + wbyte);
        gload_lds16(pAl + k0 + 16, (char*)Asl + wbyte + 8192);
        gload_lds16(pBh + k0,      (char*)Bsh + wbyte);
        gload_lds16(pBh + k0 + 16, (char*)Bsh + wbyte + 8192);
        gload_lds16(pBl + k0,      (char*)Bsl + wbyte);
        gload_lds16(pBl + k0 + 16, (char*)Bsl + wbyte + 8192);
        __syncthreads();                       // drains vmcnt: tile ready

        bf16x8 bh[4], bl[4];
        #pragma unroll
        for (int j = 0; j < 4; ++j) {
            bh[j] = BhV[q * 256 + wn + j * 16 + r16];
            bl[j] = BlV[q * 256 + wn + j * 16 + r16];
        }
        __builtin_amdgcn_s_setprio(1);
        #pragma unroll
        for (int i = 0; i < 8; ++i) {
            const bf16x8 ah = AhV[q * 256 + wm + i * 16 + r16];
            const bf16x8 al = AlV[q * 256 + wm + i * 16 + r16];
            #pragma unroll
            for (int j = 0; j < 4; ++j) {
                acc[i][j] = __builtin_amdgcn_mfma_f32_16x16x32_bf16(
                    ah, bh[j], acc[i][j], 0, 0, 0);
                acc[i][j] = __builtin_amdgcn_mfma_f32_16x16x32_bf16(
                    al, bh[j], acc[i][j], 0, 0, 0);
                acc[i][j] = __builtin_amdgcn_mfma_f32_16x16x32_bf16(
                    ah, bl[j], acc[i][j], 0, 0, 0);
            }
        }
        __builtin_amdgcn_s_setprio(0);
    }

    // epilogue: C/D layout col = lane&15, row = (lane>>4)*4 + r
    const float cadd = add_c ? add_c[0] : 0.0f;
    const int col = lane & 15;
    const int rb  = (lane >> 4) * 4;
    #pragma unroll
    for (int j = 0; j < 4; ++j) {
        const int n = n0 + wn + j * 16 + col;
        const float bv = bias ? bias[n] : 0.0f;
        #pragma unroll
        for (int i = 0; i < 8; ++i) {
            const int m = m0 + wm + i * 16 + rb;
            f32x4 v = acc[i][j];
            #pragma unroll
            for (int r = 0; r < 4; ++r) v[r] = v[r] * alpha + cadd + bv;
            if constexpr (OUT == 0) {
                float* C = (float*)C0 + (long long)bz * sC;
                #pragma unroll
                for (int r = 0; r < 4; ++r) C[(long long)(m + r) * N + n] = v[r];
            } else if constexpr (OUT == 1) {
                bf16* Ch = (bf16*)C0 + (long long)bz * sC;
                bf16* Cl = (bf16*)C1 + (long long)bz * sC;
                #pragma unroll
                for (int r = 0; r < 4; ++r) {
                    bf16 h, l; split2(v[r], h, l);
                    Ch[(long long)(m + r) * N + n] = h;
                    Cl[(long long)(m + r) * N + n] = l;
                }
            } else {   // transposed hi/lo: CT[n][m], 4 consecutive m = 8B store
                bf16* Ch = (bf16*)C0 + (long long)bz * sC;
                bf16* Cl = (bf16*)C1 + (long long)bz * sC;
                bf16 hp[4], lp[4];
                #pragma unroll
                for (int r = 0; r < 4; ++r) split2(v[r], hp[r], lp[r]);
                *reinterpret_cast<bf16x4*>(&Ch[(long long)n * M + m]) =
                    *reinterpret_cast<bf16x4*>(hp);
                *reinterpret_cast<bf16x4*>(&Cl[(long long)n * M + m]) =
                    *reinterpret_cast<bf16x4*>(lp);
            }
        }
    }
}

// ---------------------------------------------------------------------------
// fp32 [R][Cc] -> transposed hi/lo bf16 [Cc][R]  (32x32 LDS tiles)
// ---------------------------------------------------------------------------
__global__ __launch_bounds__(256) void transpose_split_kernel(
    const float* __restrict__ in, bf16* __restrict__ oh, bf16* __restrict__ ol,
    int R, int Cc, long long sIn, long long sOut)
{
    const int b = blockIdx.z;
    in += (long long)b * sIn; oh += (long long)b * sOut; ol += (long long)b * sOut;
    __shared__ float tile[32][33];
    const int c0 = blockIdx.x * 32, r0 = blockIdx.y * 32;
    const int tx = threadIdx.x & 31, ty = threadIdx.x >> 5;   // 32 x 8
    #pragma unroll
    for (int i = 0; i < 32; i += 8)
        tile[ty + i][tx] = in[(long long)(r0 + ty + i) * Cc + (c0 + tx)];
    __syncthreads();
    #pragma unroll
    for (int i = 0; i < 32; i += 8) {
        const float v = tile[tx][ty + i];
        bf16 h, l; split2(v, h, l);
        oh[(long long)(c0 + ty + i) * R + (r0 + tx)] = h;
        ol[(long long)(c0 + ty + i) * R + (r0 + tx)] = l;
    }
}

// fp32 -> hi/lo bf16, no transpose (n multiple of 1024)
__global__ __launch_bounds__(256) void split_kernel(
    const float* __restrict__ in, bf16* __restrict__ oh, bf16* __restrict__ ol,
    long long n)
{
    const long long i = ((long long)blockIdx.x * 256 + threadIdx.x) * 4;
    if (i >= n) return;
    const float4 v = *reinterpret_cast<const float4*>(in + i);
    bf16 h[4], l[4];
    split2(v.x, h[0], l[0]); split2(v.y, h[1], l[1]);
    split2(v.z, h[2], l[2]); split2(v.w, h[3], l[3]);
    *reinterpret_cast<bf16x4*>(oh + i) = *reinterpret_cast<bf16x4*>(h);
    *reinterpret_cast<bf16x4*>(ol + i) = *reinterpret_cast<bf16x4*>(l);
}

// ---------------------------------------------------------------------------
// LayerNorm over D=1024: fp32 in -> bf16 hi/lo out. One block per row.
// ---------------------------------------------------------------------------
__global__ __launch_bounds__(256) void layernorm_split_kernel(
    const float* __restrict__ x, const float* __restrict__ g,
    const float* __restrict__ b, bf16* __restrict__ oh, bf16* __restrict__ ol)
{
    const long long row = blockIdx.x;
    const float4* xr = reinterpret_cast<const float4*>(x + row * DD);
    const int t = threadIdx.x;
    float4 v = xr[t];

    __shared__ float red[4];
    float s = v.x + v.y + v.z + v.w;
    #pragma unroll
    for (int off = 32; off; off >>= 1) s += __shfl_down(s, off);
    if ((t & 63) == 0) red[t >> 6] = s;
    __syncthreads();
    const float mean = (red[0] + red[1] + red[2] + red[3]) * (1.0f / DD);
    __syncthreads();

    const float d0 = v.x - mean, d1 = v.y - mean, d2 = v.z - mean, d3 = v.w - mean;
    float s2 = d0 * d0 + d1 * d1 + d2 * d2 + d3 * d3;
    #pragma unroll
    for (int off = 32; off; off >>= 1) s2 += __shfl_down(s2, off);
    if ((t & 63) == 0) red[t >> 6] = s2;
    __syncthreads();
    const float var = (red[0] + red[1] + red[2] + red[3]) * (1.0f / DD);
    const float rs = rsqrtf(var + 1e-5f);

    const float4 gg = reinterpret_cast<const float4*>(g)[t];
    const float4 bb = reinterpret_cast<const float4*>(b)[t];
    float o[4];
    o[0] = d0 * rs * gg.x + bb.x; o[1] = d1 * rs * gg.y + bb.y;
    o[2] = d2 * rs * gg.z + bb.z; o[3] = d3 * rs * gg.w + bb.w;
    bf16 h[4], l[4];
    #pragma unroll
    for (int r = 0; r < 4; ++r) split2(o[r], h[r], l[r]);
    reinterpret_cast<bf16x4*>(oh + row * DD)[t] = *reinterpret_cast<bf16x4*>(h);
    reinterpret_cast<bf16x4*>(ol + row * DD)[t] = *reinterpret_cast<bf16x4*>(l);
}

// LayerNorm fp32 in place (for fused, consumed by fp32 pool path)
__global__ __launch_bounds__(256) void layernorm_kernel(
    float* __restrict__ x, const float* __restrict__ g, const float* __restrict__ b)
{
    const long long row = blockIdx.x;
    float4* xr = reinterpret_cast<float4*>(x + row * DD);
    const int t = threadIdx.x;
    float4 v = xr[t];

    __shared__ float red[4];
    float s = v.x + v.y + v.z + v.w;
    #pragma unroll
    for (int off = 32; off; off >>= 1) s += __shfl_down(s, off);
    if ((t & 63) == 0) red[t >> 6] = s;
    __syncthreads();
    const float mean = (red[0] + red[1] + red[2] + red[3]) * (1.0f / DD);
    __syncthreads();

    const float d0 = v.x - mean, d1 = v.y - mean, d2 = v.z - mean, d3 = v.w - mean;
    float s2 = d0 * d0 + d1 * d1 + d2 * d2 + d3 * d3;
    #pragma unroll
    for (int off = 32; off; off >>= 1) s2 += __shfl_down(s2, off);
    if ((t & 63) == 0) red[t >> 6] = s2;
    __syncthreads();
    const float var = (red[0] + red[1] + red[2] + red[3]) * (1.0f / DD);
    const float rs = rsqrtf(var + 1e-5f);

    const float4 gg = reinterpret_cast<const float4*>(g)[t];
    const float4 bb = reinterpret_cast<const float4*>(b)[t];
    v.x = d0 * rs * gg.x + bb.x;
    v.y = d1 * rs * gg.y + bb.y;
    v.z = d2 * rs * gg.z + bb.z;
    v.w = d3 * rs * gg.w + bb.w;
    xr[t] = v;
}

// ---------------------------------------------------------------------------
// Row softmax over 512 cols, fp32 in -> bf16 hi/lo out (attn weights)
// ---------------------------------------------------------------------------
__global__ __launch_bounds__(256) void softmax512_split_kernel(
    const float* __restrict__ x, bf16* __restrict__ oh, bf16* __restrict__ ol)
{
    const long long row = blockIdx.x;
    const float2 v = reinterpret_cast<const float2*>(x + row * 512)[threadIdx.x];
    const int t = threadIdx.x;

    __shared__ float red[4];
    float mx = fmaxf(v.x, v.y);
    #pragma unroll
    for (int off = 32; off; off >>= 1) mx = fmaxf(mx, __shfl_down(mx, off));
    if ((t & 63) == 0) red[t >> 6] = mx;
    __syncthreads();
    mx = fmaxf(fmaxf(red[0], red[1]), fmaxf(red[2], red[3]));
    __syncthreads();

    const float e0 = expf(v.x - mx), e1 = expf(v.y - mx);
    float s = e0 + e1;
    #pragma unroll
    for (int off = 32; off; off >>= 1) s += __shfl_down(s, off);
    if ((t & 63) == 0) red[t >> 6] = s;
    __syncthreads();
    s = red[0] + red[1] + red[2] + red[3];
    const float inv = 1.0f / s;

    bf16 h0, l0, h1, l1;
    split2(e0 * inv, h0, l0); split2(e1 * inv, h1, l1);
    bf16x2 hh = {h0, h1}, ll = {l0, l1};
    reinterpret_cast<bf16x2*>(oh + row * 512)[t] = hh;
    reinterpret_cast<bf16x2*>(ol + row * 512)[t] = ll;
}

// fp32 row softmax over 512 in place (pool weights)
__global__ __launch_bounds__(256) void softmax512_kernel(float* __restrict__ x)
{
    const long long row = blockIdx.x;
    float2* xr = reinterpret_cast<float2*>(x + row * 512);
    const int t = threadIdx.x;
    float2 v = xr[t];

    __shared__ float red[4];
    float mx = fmaxf(v.x, v.y);
    #pragma unroll
    for (int off = 32; off; off >>= 1) mx = fmaxf(mx, __shfl_down(mx, off));
    if ((t & 63) == 0) red[t >> 6] = mx;
    __syncthreads();
    mx = fmaxf(fmaxf(red[0], red[1]), fmaxf(red[2], red[3]));
    __syncthreads();

    const float e0 = expf(v.x - mx), e1 = expf(v.y - mx);
    float s = e0 + e1;
    #pragma unroll
    for (int off = 32; off; off >>= 1) s += __shfl_down(s, off);
    if ((t & 63) == 0) red[t >> 6] = s;
    __syncthreads();
    s = red[0] + red[1] + red[2] + red[3];
    const float inv = 1.0f / s;
    xr[t] = make_float2(e0 * inv, e1 * inv);
}

// ---------------------------------------------------------------------------
// fp32 tiled GEMM (kept for the small pool / fc head ops)
// ---------------------------------------------------------------------------
#define BM 64
#define BN 64
#define BK 16

template <int TA, int TB, int ACT>
__global__ __launch_bounds__(256) void gemm_kernel(
    const float* __restrict__ A, const float* __restrict__ B,
    const float* __restrict__ bias, const float* __restrict__ add_const_ptr,
    float* __restrict__ C,
    int M, int N, int K,
    long long strideA, long long strideB, long long strideC,
    float alpha)
{
    const int batch = blockIdx.z;
    A += (long long)batch * strideA;
    B += (long long)batch * strideB;
    C += (long long)batch * strideC;

    __shared__ float As[BK][BM + 4];
    __shared__ float Bs[BK][BN + 4];

    const int t  = threadIdx.x;
    const int tx = t & 15;
    const int ty = t >> 4;
    const int m0 = blockIdx.y * BM;
    const int n0 = blockIdx.x * BN;

    float acc[4][4] = {};

    for (int k0 = 0; k0 < K; k0 += BK) {
        if (TA == 0) {
            const int mm = t >> 2;
            const int kk = (t & 3) * 4;
            const float4 v = *reinterpret_cast<const float4*>(
                &A[(long long)(m0 + mm) * K + (k0 + kk)]);
            As[kk + 0][mm] = v.x; As[kk + 1][mm] = v.y;
            As[kk + 2][mm] = v.z; As[kk + 3][mm] = v.w;
        } else {
            const int kk = t >> 4;
            const int mm = (t & 15) * 4;
            const float4 v = *reinterpret_cast<const float4*>(
                &A[(long long)(k0 + kk) * M + (m0 + mm)]);
            *reinterpret_cast<float4*>(&As[kk][mm]) = v;
        }
        if (TB == 0) {
            const int kk = t >> 4;
            const int nn = (t & 15) * 4;
            const float4 v = *reinterpret_cast<const float4*>(
                &B[(long long)(k0 + kk) * N + (n0 + nn)]);
            *reinterpret_cast<float4*>(&Bs[kk][nn]) = v;
        } else {
            const int nn = t >> 2;
            const int kk = (t & 3) * 4;
            const float4 v = *reinterpret_cast<const float4*>(
                &B[(long long)(n0 + nn) * K + (k0 + kk)]);
            Bs[kk + 0][nn] = v.x; Bs[kk + 1][nn] = v.y;
            Bs[kk + 2][nn] = v.z; Bs[kk + 3][nn] = v.w;
        }
        __syncthreads();

        #pragma unroll
        for (int kk = 0; kk < BK; ++kk) {
            float a[4], b[4];
            #pragma unroll
            for (int i = 0; i < 4; ++i) a[i] = As[kk][ty * 4 + i];
            #pragma unroll
            for (int j = 0; j < 4; ++j) b[j] = Bs[kk][tx * 4 + j];
            #pragma unroll
            for (int i = 0; i < 4; ++i)
                #pragma unroll
                for (int j = 0; j < 4; ++j)
                    acc[i][j] = fmaf(a[i], b[j], acc[i][j]);
        }
        __syncthreads();
    }

    const float cadd = add_const_ptr ? add_const_ptr[0] : 0.0f;
    #pragma unroll
    for (int i = 0; i < 4; ++i) {
        const int m = m0 + ty * 4 + i;
        #pragma unroll
        for (int j = 0; j < 4; ++j) {
            const int n = n0 + tx * 4 + j;
            float v = acc[i][j] * alpha + cadd;
            if (bias) v += bias[n];
            if (ACT == 1) v = (v > 0.0f) ? v : 0.01f * v;
            else if (ACT == 2) v = 0.5f * v * (1.0f + erff(v * 0.70710678118654752f));
            C[(long long)m * N + n] = v;
        }
    }
}

// pool_scores[row] = h[row,:64] . Wp2 + bp2
__global__ __launch_bounds__(256) void pool_score_kernel(
    const float* __restrict__ h, const float* __restrict__ Wp2,
    const float* __restrict__ bp2, float* __restrict__ out)
{
    const int row  = blockIdx.x * 4 + (threadIdx.x >> 6);
    const int lane = threadIdx.x & 63;
    float v = h[(long long)row * HH + lane] * Wp2[lane];
    #pragma unroll
    for (int off = 32; off; off >>= 1) v += __shfl_down(v, off);
    if (lane == 0) out[row] = v + bp2[0];
}

// pooled[b,d] = sum_n fused[b,n,d] * w[b,n]
__global__ __launch_bounds__(256) void pooled_kernel(
    const float* __restrict__ fused, const float* __restrict__ w,
    float* __restrict__ out)
{
    const int b = blockIdx.y;
    const int d = blockIdx.x * 256 + threadIdx.x;
    __shared__ float ws_[CC_];
    for (int i = threadIdx.x; i < CC_; i += 256) ws_[i] = w[(long long)b * CC_ + i];
    __syncthreads();
    float acc = 0.0f;
    const float* fb = fused + (long long)b * CC_ * DD + d;
    for (int n = 0; n < CC_; ++n) acc = fmaf(fb[(long long)n * DD], ws_[n], acc);
    out[(long long)b * DD + d] = acc;
}

// rul[b] = |h2[b,:] . Wf3 + bf3|
__global__ __launch_bounds__(256) void rul_kernel(
    const float* __restrict__ h2, const float* __restrict__ Wf3,
    const float* __restrict__ bf3, float* __restrict__ out)
{
    const int b = blockIdx.x;
    const int t = threadIdx.x;
    float acc = 0.0f;
    for (int k = t; k < DF_; k += 256)
        acc = fmaf(h2[(long long)b * DF_ + k], Wf3[k], acc);
    __shared__ float red[4];
    #pragma unroll
    for (int off = 32; off; off >>= 1) acc += __shfl_down(acc, off);
    if ((t & 63) == 0) red[t >> 6] = acc;
    __syncthreads();
    if (t == 0) out[b] = fabsf(red[0] + red[1] + red[2] + red[3] + bf3[0]);
}

// ---------------------------------------------------------------------------
// Launch
// ---------------------------------------------------------------------------
extern "C" void kernel_launch(void* const* d_in, const int* in_sizes, int n_in,
                              void* d_out, int out_size, void* d_ws, size_t ws_size,
                              hipStream_t stream)
{
    const float* x_enc   = (const float*)d_in[0];
    const float* W_emb   = (const float*)d_in[2];
    const float* b_emb   = (const float*)d_in[3];
    const float* g_s     = (const float*)d_in[4];
    const float* b_s     = (const float*)d_in[5];
    const float* basis   = (const float*)d_in[6];
    const float* Wq      = (const float*)d_in[7];
    const float* bq      = (const float*)d_in[8];
    const float* Wk      = (const float*)d_in[9];
    const float* bk      = (const float*)d_in[10];
    const float* Wv      = (const float*)d_in[11];
    const float* bv      = (const float*)d_in[12];
    const float* age_sc  = (const float*)d_in[13];
    const float* g_f     = (const float*)d_in[14];
    const float* b_f     = (const float*)d_in[15];
    const float* Wp1     = (const float*)d_in[16];
    const float* bp1     = (const float*)d_in[17];
    const float* Wp2     = (const float*)d_in[18];
    const float* bp2     = (const float*)d_in[19];
    const float* Wf1     = (const float*)d_in[20];
    const float* bf1     = (const float*)d_in[21];
    const float* Wf2     = (const float*)d_in[22];
    const float* bf2     = (const float*)d_in[23];
    const float* Wf3     = (const float*)d_in[24];
    const float* bf3     = (const float*)d_in[25];
    float* out = (float*)d_out;
    (void)in_sizes; (void)n_in; (void)out_size; (void)ws_size;

    // ---- workspace layout (MB offsets, liveness-reused; peak = 896 MB) ----
    const unsigned long long MBy = 1048576ULL;
    char* ws = (char*)d_ws;
    bf16* xT_h   = (bf16*)(ws + 0 * MBy);      // [B][C][T]   ph1-2
    bf16* xT_l   = (bf16*)(ws + 128 * MBy);
    float* sens_f= (float*)(ws + 256 * MBy);   // [B][C][D]   ph2-3
    bf16* WT_h   = (bf16*)(ws + 512 * MBy);    // W_embT / WqT slot (transient)
    bf16* WT_l   = (bf16*)(ws + 514 * MBy);
    bf16* sens_h = (bf16*)(ws + 0 * MBy);      // ph3-V
    bf16* sens_l = (bf16*)(ws + 128 * MBy);
    bf16* Q_h    = (bf16*)(ws + 256 * MBy);    // ph4-S2
    bf16* Q_l    = (bf16*)(ws + 384 * MBy);
    bf16* WkT_h  = (bf16*)(ws + 768 * MBy);    // transient
    bf16* WkT_l  = (bf16*)(ws + 770 * MBy);
    bf16* K_h    = (bf16*)(ws + 512 * MBy);    // ph5-S1
    bf16* K_l    = (bf16*)(ws + 640 * MBy);
    bf16* S1T_h  = (bf16*)(ws + 768 * MBy);    // [B][C][C]^T  ph6-S3
    bf16* S1T_l  = (bf16*)(ws + 832 * MBy);
    bf16* bas_h  = (bf16*)(ws + 512 * MBy);    // ph7 (K dead)
    bf16* bas_l  = (bf16*)(ws + 513 * MBy);
    bf16* S2T_h  = (bf16*)(ws + 520 * MBy);    // ph7-S3
    bf16* S2T_l  = (bf16*)(ws + 584 * MBy);
    float* S3    = (float*)(ws + 256 * MBy);   // [B][C][C]    ph8-9 (Q dead)
    bf16* at_h   = (bf16*)(ws + 384 * MBy);    // attn hi/lo   ph9-fused
    bf16* at_l   = (bf16*)(ws + 448 * MBy);
    bf16* WvT_h  = (bf16*)(ws + 768 * MBy);    // transient (S1T dead)
    bf16* WvT_l  = (bf16*)(ws + 770 * MBy);
    bf16* VT_h   = (bf16*)(ws + 512 * MBy);    // [B][D][C]    ph10-fused
    bf16* VT_l   = (bf16*)(ws + 640 * MBy);
    float* fusedp= (float*)(ws + 0 * MBy);     // [B][C][D]    (sensor dead)
    float* hpool = (float*)(ws + 256 * MBy);
    float* pscr  = (float*)(ws + 272 * MBy);
    float* pooled= (float*)(ws + 273 * MBy);
    float* h1    = (float*)(ws + 274 * MBy);
    float* h2    = (float*)(ws + 276 * MBy);

    const long long CD  = (long long)CC_ * DD;   // 524288
    const long long CCs = (long long)CC_ * CC_;  // 262144
    const dim3 blk(256);
    const dim3 blkG(512);

    // 1. x_enc [B][T][C] -> xT hi/lo [B][C][T]
    transpose_split_kernel<<<dim3(CC_ / 32, TT / 32, BB), blk, 0, stream>>>(
        x_enc, xT_h, xT_l, TT, CC_, (long long)TT * CC_, (long long)CC_ * TT);
    // 2. W_emb [T][D] -> W_embT hi/lo [D][T]
    transpose_split_kernel<<<dim3(DD / 32, TT / 32, 1), blk, 0, stream>>>(
        W_emb, WT_h, WT_l, TT, DD, 0, 0);
    // 3. sensor = xT @ W_embT^T + b_emb   (fp32 out)
    mfma_gemm<0><<<dim3(DD / 256, CC_ / 256, BB), blkG, 0, stream>>>(
        xT_h, xT_l, WT_h, WT_l, b_emb, nullptr, sens_f, nullptr,
        CC_, DD, TT, TT, TT, (long long)CC_ * TT, 0, CD, 1.0f);
    // 4. LayerNorm(sensor) -> hi/lo
    layernorm_split_kernel<<<BB * CC_, blk, 0, stream>>>(sens_f, g_s, b_s, sens_h, sens_l);
    // 5. Wq -> WqT hi/lo; Q = sensor @ Wq + bq -> hi/lo
    transpose_split_kernel<<<dim3(DD / 32, DD / 32, 1), blk, 0, stream>>>(
        Wq, WT_h, WT_l, DD, DD, 0, 0);
    mfma_gemm<1><<<dim3(DD / 256, (BB * CC_) / 256, 1), blkG, 0, stream>>>(
        sens_h, sens_l, WT_h, WT_l, bq, nullptr, Q_h, Q_l,
        BB * CC_, DD, DD, DD, DD, 0, 0, 0, 1.0f);
    // 6. Wk -> WkT hi/lo; K = sensor @ Wk + bk -> hi/lo
    transpose_split_kernel<<<dim3(DD / 32, DD / 32, 1), blk, 0, stream>>>(
        Wk, WkT_h, WkT_l, DD, DD, 0, 0);
    mfma_gemm<1><<<dim3(DD / 256, (BB * CC_) / 256, 1), blkG, 0, stream>>>(
        sens_h, sens_l, WkT_h, WkT_l, bk, nullptr, K_h, K_l,
        BB * CC_, DD, DD, DD, DD, 0, 0, 0, 1.0f);
    // 7. S1T = (Q K^T / 32 + age)^T  hi/lo  (transposed epilogue)
    mfma_gemm<2><<<dim3(CC_ / 256, CC_ / 256, BB), blkG, 0, stream>>>(
        Q_h, Q_l, K_h, K_l, nullptr, age_sc, S1T_h, S1T_l,
        CC_, CC_, DD, DD, DD, CD, CD, CCs, INV_SQRT_D);
    // 8. basis split; S2T = (Q basis^T / 32)^T hi/lo
    split_kernel<<<(CC_ * DD) / 1024, blk, 0, stream>>>(
        basis, bas_h, bas_l, (long long)CC_ * DD);
    mfma_gemm<2><<<dim3(CC_ / 256, CC_ / 256, BB), blkG, 0, stream>>>(
        Q_h, Q_l, bas_h, bas_l, nullptr, nullptr, S2T_h, S2T_l,
        CC_, CC_, DD, DD, DD, CD, 0, CCs, INV_SQRT_D);
    // 9. S3[n,k] = sum_j S2T[n,j]*S1T[k,j]   (fp32 out)
    mfma_gemm<0><<<dim3(CC_ / 256, CC_ / 256, BB), blkG, 0, stream>>>(
        S2T_h, S2T_l, S1T_h, S1T_l, nullptr, nullptr, S3, nullptr,
        CC_, CC_, CC_, CC_, CC_, CCs, CCs, CCs, 1.0f);
    // 10. attn = softmax(S3) -> hi/lo
    softmax512_split_kernel<<<BB * CC_, blk, 0, stream>>>(S3, at_h, at_l);
    // 11. Wv -> WvT hi/lo; VT = (sensor @ Wv + bv)^T hi/lo  [B][D][C]
    transpose_split_kernel<<<dim3(DD / 32, DD / 32, 1), blk, 0, stream>>>(
        Wv, WvT_h, WvT_l, DD, DD, 0, 0);
    mfma_gemm<2><<<dim3(DD / 256, CC_ / 256, BB), blkG, 0, stream>>>(
        sens_h, sens_l, WvT_h, WvT_l, bv, nullptr, VT_h, VT_l,
        CC_, DD, DD, DD, DD, CD, 0, (long long)DD * CC_, 1.0f);
    // 12. fused[n,d] = sum_m attn[n,m] * VT[d,m] / 32   (fp32 out)
    mfma_gemm<0><<<dim3(DD / 256, CC_ / 256, BB), blkG, 0, stream>>>(
        at_h, at_l, VT_h, VT_l, nullptr, nullptr, fusedp, nullptr,
        CC_, DD, CC_, CC_, CC_, CCs, (long long)DD * CC_, CD, INV_SQRT_D);
    // 13. LayerNorm(fused) in place (fp32)
    layernorm_kernel<<<BB * CC_, blk, 0, stream>>>(fusedp, g_f, b_f);
    // 14. hpool = gelu(fused @ Wp1 + bp1)  (fp32 path)
    gemm_kernel<0, 0, 2><<<dim3(HH / 64, (BB * CC_) / 64, 1), blk, 0, stream>>>(
        fusedp, Wp1, bp1, nullptr, hpool, BB * CC_, HH, DD, 0, 0, 0, 1.0f);
    // 15. pool scores + softmax over C
    pool_score_kernel<<<(BB * CC_) / 4, blk, 0, stream>>>(hpool, Wp2, bp2, pscr);
    softmax512_kernel<<<BB, blk, 0, stream>>>(pscr);
    // 16. pooled
    pooled_kernel<<<dim3(DD / 256, BB), blk, 0, stream>>>(fusedp, pscr, pooled);
    // 17. fc head
    gemm_kernel<0, 0, 1><<<dim3(DF_ / 64, BB / 64, 1), blk, 0, stream>>>(
        pooled, Wf1, bf1, nullptr, h1, BB, DF_, DD, 0, 0, 0, 1.0f);
    gemm_kernel<0, 0, 0><<<dim3(DF_ / 64, BB / 64, 1), blk, 0, stream>>>(
        h1, Wf2, bf2, nullptr, h2, BB, DF_, DF_, 0, 0, 0, 1.0f);
    rul_kernel<<<BB, blk, 0, stream>>>(h2, Wf3, bf3, out);
}

// Round 10
// 2449.896 us; speedup vs baseline: 4.4106x; 4.4106x over previous
//
#include <hip/hip_runtime.h>
#include <hip/hip_bf16.h>
#include <math.h>

// ---------------------------------------------------------------------------
// Problem constants
// ---------------------------------------------------------------------------
#define BB   128     // batch
#define TT   1024    // time
#define CC_  512     // channels / variates (N)
#define DD   1024    // model dim
#define DF_  2048    // fc hidden
#define HH   64      // pool hidden
#define INV_SQRT_D 0.03125f   // 1/sqrt(1024)

typedef _Float16 f16;
typedef __attribute__((ext_vector_type(8))) _Float16 f16x8;
typedef __attribute__((ext_vector_type(4))) _Float16 f16x4;
typedef __attribute__((ext_vector_type(2))) _Float16 f16x2;
typedef __attribute__((ext_vector_type(4))) float f32x4;

__device__ __forceinline__ void gload_lds16(const void* g, void* l) {
    // async global->LDS, 16B per lane; LDS dest = wave-uniform base + lane*16
    __builtin_amdgcn_global_load_lds(
        (const __attribute__((address_space(1))) void*)g,
        (__attribute__((address_space(3))) void*)l, 16, 0, 0);
}

// ---------------------------------------------------------------------------
// fp16 MFMA GEMM (fp32 accumulate).
//   C[m,n] = alpha*sum_k A[m,k]*B[n,k] + add_c + bias[n]
//   A stored [M][K] (lda); B stored [N][K] (ldb), k-contiguous fp16.
//   OUT: 0 = fp32 C[M][N];  1 = fp16 C[M][N];  2 = fp16 C^T[N][M]
// Tile 256x256, BK=32, 8 waves (512 thr); per-wave output 128x64.
// LDS: [buf=2][q=4][row=256][8] f16 per tensor = 16 KB; total 64 KB.
// Double-buffered, prefetch-before-compute (r4 structure, known good).
// M,N multiples of 256; K multiple of 32.
// ---------------------------------------------------------------------------
template <int OUT>
__global__ __launch_bounds__(512, 2) void mfma_gemm(
    const f16* __restrict__ A, const f16* __restrict__ B,
    const float* __restrict__ bias, const float* __restrict__ add_c,
    void* __restrict__ C0,
    int M, int N, int K, int lda, int ldb,
    long long sA, long long sB, long long sC, float alpha)
{
    // ---- XCD swizzle on flattened (x,y); identity when nwg % 8 != 0 ----
    const int gx = gridDim.x;
    const int nwg = gx * gridDim.y;
    int lin = blockIdx.y * gx + blockIdx.x;
    if ((nwg & 7) == 0) {
        const int cpx = nwg >> 3;
        lin = (lin & 7) * cpx + (lin >> 3);
    }
    const int bx = lin % gx, by = lin / gx;

    const int bz   = blockIdx.z;
    const int t    = threadIdx.x;
    const int wave = t >> 6, lane = t & 63;
    const int m0 = by * 256, n0 = bx * 256;
    const int wm = (wave >> 2) * 128;      // 2 M-groups of 128
    const int wn = (wave & 3) * 64;        // 4 N-groups of 64

    __shared__ __align__(16) f16 As[2][8192];   // 16 KB per buffer
    __shared__ __align__(16) f16 Bs[2][8192];

    f32x4 acc[8][4] = {};

    // staging: thread t stages 16B units (t) and (t+512) of each 16 KB tile
    //   unit u -> row = u & 255, q' = u >> 8;  LDS byte = u*16
    const int srow  = t & 255;
    const int sq8   = (t >> 8) * 8;              // k-offset: 0 or 8
    const int wbyte = wave * 1024;               // wave-uniform LDS base
    const long long aoff = (long long)bz * sA + (long long)(m0 + srow) * lda + sq8;
    const long long boff = (long long)bz * sB + (long long)(n0 + srow) * ldb + sq8;
    const f16* pA = A + aoff;
    const f16* pB = B + boff;

    const int q   = lane >> 4;   // k-chunk for fragment reads
    const int r16 = lane & 15;

    auto stage = [&](int k0, int b) {
        char* lA = (char*)(&As[b][0]) + wbyte;
        char* lB = (char*)(&Bs[b][0]) + wbyte;
        gload_lds16(pA + k0,      lA);
        gload_lds16(pA + k0 + 16, lA + 8192);
        gload_lds16(pB + k0,      lB);
        gload_lds16(pB + k0 + 16, lB + 8192);
    };

    stage(0, 0);
    __syncthreads();              // drains vmcnt: buf0 ready
    int cur = 0;

    for (int k0 = 0; k0 < K; k0 += 32) {
        if (k0 + 32 < K) stage(k0 + 32, cur ^ 1);   // prefetch next tile

        const f16x8* AV = (const f16x8*)(&As[cur][0]);
        const f16x8* BV = (const f16x8*)(&Bs[cur][0]);

        f16x8 bfr[4];
        #pragma unroll
        for (int j = 0; j < 4; ++j)
            bfr[j] = BV[q * 256 + wn + j * 16 + r16];
        __builtin_amdgcn_s_setprio(1);
        #pragma unroll
        for (int i = 0; i < 8; ++i) {
            const f16x8 a = AV[q * 256 + wm + i * 16 + r16];
            #pragma unroll
            for (int j = 0; j < 4; ++j)
                acc[i][j] = __builtin_amdgcn_mfma_f32_16x16x32_f16(
                    a, bfr[j], acc[i][j], 0, 0, 0);
        }
        __builtin_amdgcn_s_setprio(0);
        __syncthreads();           // next buf ready / LDS free
        cur ^= 1;
    }

    // epilogue: C/D layout col = lane&15, row = (lane>>4)*4 + r
    const float cadd = add_c ? add_c[0] : 0.0f;
    const int col = lane & 15;
    const int rb  = (lane >> 4) * 4;
    #pragma unroll
    for (int j = 0; j < 4; ++j) {
        const int n = n0 + wn + j * 16 + col;
        const float bv = bias ? bias[n] : 0.0f;
        #pragma unroll
        for (int i = 0; i < 8; ++i) {
            const int m = m0 + wm + i * 16 + rb;
            f32x4 v = acc[i][j];
            #pragma unroll
            for (int r = 0; r < 4; ++r) v[r] = v[r] * alpha + cadd + bv;
            if constexpr (OUT == 0) {
                float* C = (float*)C0 + (long long)bz * sC;
                #pragma unroll
                for (int r = 0; r < 4; ++r) C[(long long)(m + r) * N + n] = v[r];
            } else if constexpr (OUT == 1) {
                f16* C = (f16*)C0 + (long long)bz * sC;
                #pragma unroll
                for (int r = 0; r < 4; ++r)
                    C[(long long)(m + r) * N + n] = (f16)v[r];
            } else {   // transposed: CT[n][m], 4 consecutive m = 8B store
                f16* C = (f16*)C0 + (long long)bz * sC;
                f16 p[4];
                #pragma unroll
                for (int r = 0; r < 4; ++r) p[r] = (f16)v[r];
                *reinterpret_cast<f16x4*>(&C[(long long)n * M + m]) =
                    *reinterpret_cast<f16x4*>(p);
            }
        }
    }
}

// ---------------------------------------------------------------------------
// fp32 [R][Cc] -> transposed fp16 [Cc][R]  (32x32 LDS tiles)
// ---------------------------------------------------------------------------
__global__ __launch_bounds__(256) void transpose_h_kernel(
    const float* __restrict__ in, f16* __restrict__ o,
    int R, int Cc, long long sIn, long long sOut)
{
    const int b = blockIdx.z;
    in += (long long)b * sIn; o += (long long)b * sOut;
    __shared__ float tile[32][33];
    const int c0 = blockIdx.x * 32, r0 = blockIdx.y * 32;
    const int tx = threadIdx.x & 31, ty = threadIdx.x >> 5;   // 32 x 8
    #pragma unroll
    for (int i = 0; i < 32; i += 8)
        tile[ty + i][tx] = in[(long long)(r0 + ty + i) * Cc + (c0 + tx)];
    __syncthreads();
    #pragma unroll
    for (int i = 0; i < 32; i += 8)
        o[(long long)(c0 + ty + i) * R + (r0 + tx)] = (f16)tile[tx][ty + i];
}

// fp32 -> fp16 flat (n multiple of 1024)
__global__ __launch_bounds__(256) void cvt_h_kernel(
    const float* __restrict__ in, f16* __restrict__ o, long long n)
{
    const long long i = ((long long)blockIdx.x * 256 + threadIdx.x) * 4;
    if (i >= n) return;
    const float4 v = *reinterpret_cast<const float4*>(in + i);
    f16 p[4] = {(f16)v.x, (f16)v.y, (f16)v.z, (f16)v.w};
    *reinterpret_cast<f16x4*>(o + i) = *reinterpret_cast<f16x4*>(p);
}

// ---------------------------------------------------------------------------
// LayerNorm over D=1024: fp32 in -> fp16 out. One block per row.
// ---------------------------------------------------------------------------
__global__ __launch_bounds__(256) void layernorm_h_kernel(
    const float* __restrict__ x, const float* __restrict__ g,
    const float* __restrict__ b, f16* __restrict__ o)
{
    const long long row = blockIdx.x;
    const float4* xr = reinterpret_cast<const float4*>(x + row * DD);
    const int t = threadIdx.x;
    float4 v = xr[t];

    __shared__ float red[4];
    float s = v.x + v.y + v.z + v.w;
    #pragma unroll
    for (int off = 32; off; off >>= 1) s += __shfl_down(s, off);
    if ((t & 63) == 0) red[t >> 6] = s;
    __syncthreads();
    const float mean = (red[0] + red[1] + red[2] + red[3]) * (1.0f / DD);
    __syncthreads();

    const float d0 = v.x - mean, d1 = v.y - mean, d2 = v.z - mean, d3 = v.w - mean;
    float s2 = d0 * d0 + d1 * d1 + d2 * d2 + d3 * d3;
    #pragma unroll
    for (int off = 32; off; off >>= 1) s2 += __shfl_down(s2, off);
    if ((t & 63) == 0) red[t >> 6] = s2;
    __syncthreads();
    const float var = (red[0] + red[1] + red[2] + red[3]) * (1.0f / DD);
    const float rs = rsqrtf(var + 1e-5f);

    const float4 gg = reinterpret_cast<const float4*>(g)[t];
    const float4 bb = reinterpret_cast<const float4*>(b)[t];
    f16 p[4];
    p[0] = (f16)(d0 * rs * gg.x + bb.x);
    p[1] = (f16)(d1 * rs * gg.y + bb.y);
    p[2] = (f16)(d2 * rs * gg.z + bb.z);
    p[3] = (f16)(d3 * rs * gg.w + bb.w);
    reinterpret_cast<f16x4*>(o + row * DD)[t] = *reinterpret_cast<f16x4*>(p);
}

// LayerNorm fp32 in place (for fused, consumed by fp32 pool path)
__global__ __launch_bounds__(256) void layernorm_kernel(
    float* __restrict__ x, const float* __restrict__ g, const float* __restrict__ b)
{
    const long long row = blockIdx.x;
    float4* xr = reinterpret_cast<float4*>(x + row * DD);
    const int t = threadIdx.x;
    float4 v = xr[t];

    __shared__ float red[4];
    float s = v.x + v.y + v.z + v.w;
    #pragma unroll
    for (int off = 32; off; off >>= 1) s += __shfl_down(s, off);
    if ((t & 63) == 0) red[t >> 6] = s;
    __syncthreads();
    const float mean = (red[0] + red[1] + red[2] + red[3]) * (1.0f / DD);
    __syncthreads();

    const float d0 = v.x - mean, d1 = v.y - mean, d2 = v.z - mean, d3 = v.w - mean;
    float s2 = d0 * d0 + d1 * d1 + d2 * d2 + d3 * d3;
    #pragma unroll
    for (int off = 32; off; off >>= 1) s2 += __shfl_down(s2, off);
    if ((t & 63) == 0) red[t >> 6] = s2;
    __syncthreads();
    const float var = (red[0] + red[1] + red[2] + red[3]) * (1.0f / DD);
    const float rs = rsqrtf(var + 1e-5f);

    const float4 gg = reinterpret_cast<const float4*>(g)[t];
    const float4 bb = reinterpret_cast<const float4*>(b)[t];
    v.x = d0 * rs * gg.x + bb.x;
    v.y = d1 * rs * gg.y + bb.y;
    v.z = d2 * rs * gg.z + bb.z;
    v.w = d3 * rs * gg.w + bb.w;
    xr[t] = v;
}

// ---------------------------------------------------------------------------
// Row softmax over 512 cols, fp32 in -> fp16 out (attn weights)
// ---------------------------------------------------------------------------
__global__ __launch_bounds__(256) void softmax512_h_kernel(
    const float* __restrict__ x, f16* __restrict__ o)
{
    const long long row = blockIdx.x;
    const float2 v = reinterpret_cast<const float2*>(x + row * 512)[threadIdx.x];
    const int t = threadIdx.x;

    __shared__ float red[4];
    float mx = fmaxf(v.x, v.y);
    #pragma unroll
    for (int off = 32; off; off >>= 1) mx = fmaxf(mx, __shfl_down(mx, off));
    if ((t & 63) == 0) red[t >> 6] = mx;
    __syncthreads();
    mx = fmaxf(fmaxf(red[0], red[1]), fmaxf(red[2], red[3]));
    __syncthreads();

    const float e0 = expf(v.x - mx), e1 = expf(v.y - mx);
    float s = e0 + e1;
    #pragma unroll
    for (int off = 32; off; off >>= 1) s += __shfl_down(s, off);
    if ((t & 63) == 0) red[t >> 6] = s;
    __syncthreads();
    s = red[0] + red[1] + red[2] + red[3];
    const float inv = 1.0f / s;

    f16 p[2] = {(f16)(e0 * inv), (f16)(e1 * inv)};
    reinterpret_cast<f16x2*>(o + row * 512)[t] = *reinterpret_cast<f16x2*>(p);
}

// fp32 row softmax over 512 in place (pool weights)
__global__ __launch_bounds__(256) void softmax512_kernel(float* __restrict__ x)
{
    const long long row = blockIdx.x;
    float2* xr = reinterpret_cast<float2*>(x + row * 512);
    const int t = threadIdx.x;
    float2 v = xr[t];

    __shared__ float red[4];
    float mx = fmaxf(v.x, v.y);
    #pragma unroll
    for (int off = 32; off; off >>= 1) mx = fmaxf(mx, __shfl_down(mx, off));
    if ((t & 63) == 0) red[t >> 6] = mx;
    __syncthreads();
    mx = fmaxf(fmaxf(red[0], red[1]), fmaxf(red[2], red[3]));
    __syncthreads();

    const float e0 = expf(v.x - mx), e1 = expf(v.y - mx);
    float s = e0 + e1;
    #pragma unroll
    for (int off = 32; off; off >>= 1) s += __shfl_down(s, off);
    if ((t & 63) == 0) red[t >> 6] = s;
    __syncthreads();
    s = red[0] + red[1] + red[2] + red[3];
    const float inv = 1.0f / s;
    xr[t] = make_float2(e0 * inv, e1 * inv);
}

// ---------------------------------------------------------------------------
// fp32 tiled GEMM (kept for the small pool / fc head ops)
// ---------------------------------------------------------------------------
#define BM 64
#define BN 64
#define BK 16

template <int TA, int TB, int ACT>
__global__ __launch_bounds__(256) void gemm_kernel(
    const float* __restrict__ A, const float* __restrict__ B,
    const float* __restrict__ bias, const float* __restrict__ add_const_ptr,
    float* __restrict__ C,
    int M, int N, int K,
    long long strideA, long long strideB, long long strideC,
    float alpha)
{
    const int batch = blockIdx.z;
    A += (long long)batch * strideA;
    B += (long long)batch * strideB;
    C += (long long)batch * strideC;

    __shared__ float As[BK][BM + 4];
    __shared__ float Bs[BK][BN + 4];

    const int t  = threadIdx.x;
    const int tx = t & 15;
    const int ty = t >> 4;
    const int m0 = blockIdx.y * BM;
    const int n0 = blockIdx.x * BN;

    float acc[4][4] = {};

    for (int k0 = 0; k0 < K; k0 += BK) {
        if (TA == 0) {
            const int mm = t >> 2;
            const int kk = (t & 3) * 4;
            const float4 v = *reinterpret_cast<const float4*>(
                &A[(long long)(m0 + mm) * K + (k0 + kk)]);
            As[kk + 0][mm] = v.x; As[kk + 1][mm] = v.y;
            As[kk + 2][mm] = v.z; As[kk + 3][mm] = v.w;
        } else {
            const int kk = t >> 4;
            const int mm = (t & 15) * 4;
            const float4 v = *reinterpret_cast<const float4*>(
                &A[(long long)(k0 + kk) * M + (m0 + mm)]);
            *reinterpret_cast<float4*>(&As[kk][mm]) = v;
        }
        if (TB == 0) {
            const int kk = t >> 4;
            const int nn = (t & 15) * 4;
            const float4 v = *reinterpret_cast<const float4*>(
                &B[(long long)(k0 + kk) * N + (n0 + nn)]);
            *reinterpret_cast<float4*>(&Bs[kk][nn]) = v;
        } else {
            const int nn = t >> 2;
            const int kk = (t & 3) * 4;
            const float4 v = *reinterpret_cast<const float4*>(
                &B[(long long)(n0 + nn) * K + (k0 + kk)]);
            Bs[kk + 0][nn] = v.x; Bs[kk + 1][nn] = v.y;
            Bs[kk + 2][nn] = v.z; Bs[kk + 3][nn] = v.w;
        }
        __syncthreads();

        #pragma unroll
        for (int kk = 0; kk < BK; ++kk) {
            float a[4], b[4];
            #pragma unroll
            for (int i = 0; i < 4; ++i) a[i] = As[kk][ty * 4 + i];
            #pragma unroll
            for (int j = 0; j < 4; ++j) b[j] = Bs[kk][tx * 4 + j];
            #pragma unroll
            for (int i = 0; i < 4; ++i)
                #pragma unroll
                for (int j = 0; j < 4; ++j)
                    acc[i][j] = fmaf(a[i], b[j], acc[i][j]);
        }
        __syncthreads();
    }

    const float cadd = add_const_ptr ? add_const_ptr[0] : 0.0f;
    #pragma unroll
    for (int i = 0; i < 4; ++i) {
        const int m = m0 + ty * 4 + i;
        #pragma unroll
        for (int j = 0; j < 4; ++j) {
            const int n = n0 + tx * 4 + j;
            float v = acc[i][j] * alpha + cadd;
            if (bias) v += bias[n];
            if (ACT == 1) v = (v > 0.0f) ? v : 0.01f * v;
            else if (ACT == 2) v = 0.5f * v * (1.0f + erff(v * 0.70710678118654752f));
            C[(long long)m * N + n] = v;
        }
    }
}

// pool_scores[row] = h[row,:64] . Wp2 + bp2
__global__ __launch_bounds__(256) void pool_score_kernel(
    const float* __restrict__ h, const float* __restrict__ Wp2,
    const float* __restrict__ bp2, float* __restrict__ out)
{
    const int row  = blockIdx.x * 4 + (threadIdx.x >> 6);
    const int lane = threadIdx.x & 63;
    float v = h[(long long)row * HH + lane] * Wp2[lane];
    #pragma unroll
    for (int off = 32; off; off >>= 1) v += __shfl_down(v, off);
    if (lane == 0) out[row] = v + bp2[0];
}

// pooled[b,d] = sum_n fused[b,n,d] * w[b,n]
__global__ __launch_bounds__(256) void pooled_kernel(
    const float* __restrict__ fused, const float* __restrict__ w,
    float* __restrict__ out)
{
    const int b = blockIdx.y;
    const int d = blockIdx.x * 256 + threadIdx.x;
    __shared__ float ws_[CC_];
    for (int i = threadIdx.x; i < CC_; i += 256) ws_[i] = w[(long long)b * CC_ + i];
    __syncthreads();
    float acc = 0.0f;
    const float* fb = fused + (long long)b * CC_ * DD + d;
    for (int n = 0; n < CC_; ++n) acc = fmaf(fb[(long long)n * DD], ws_[n], acc);
    out[(long long)b * DD + d] = acc;
}

// rul[b] = |h2[b,:] . Wf3 + bf3|
__global__ __launch_bounds__(256) void rul_kernel(
    const float* __restrict__ h2, const float* __restrict__ Wf3,
    const float* __restrict__ bf3, float* __restrict__ out)
{
    const int b = blockIdx.x;
    const int t = threadIdx.x;
    float acc = 0.0f;
    for (int k = t; k < DF_; k += 256)
        acc = fmaf(h2[(long long)b * DF_ + k], Wf3[k], acc);
    __shared__ float red[4];
    #pragma unroll
    for (int off = 32; off; off >>= 1) acc += __shfl_down(acc, off);
    if ((t & 63) == 0) red[t >> 6] = acc;
    __syncthreads();
    if (t == 0) out[b] = fabsf(red[0] + red[1] + red[2] + red[3] + bf3[0]);
}

// ---------------------------------------------------------------------------
// Launch
// ---------------------------------------------------------------------------
extern "C" void kernel_launch(void* const* d_in, const int* in_sizes, int n_in,
                              void* d_out, int out_size, void* d_ws, size_t ws_size,
                              hipStream_t stream)
{
    const float* x_enc   = (const float*)d_in[0];
    const float* W_emb   = (const float*)d_in[2];
    const float* b_emb   = (const float*)d_in[3];
    const float* g_s     = (const float*)d_in[4];
    const float* b_s     = (const float*)d_in[5];
    const float* basis   = (const float*)d_in[6];
    const float* Wq      = (const float*)d_in[7];
    const float* bq      = (const float*)d_in[8];
    const float* Wk      = (const float*)d_in[9];
    const float* bk      = (const float*)d_in[10];
    const float* Wv      = (const float*)d_in[11];
    const float* bv      = (const float*)d_in[12];
    const float* age_sc  = (const float*)d_in[13];
    const float* g_f     = (const float*)d_in[14];
    const float* b_f     = (const float*)d_in[15];
    const float* Wp1     = (const float*)d_in[16];
    const float* bp1     = (const float*)d_in[17];
    const float* Wp2     = (const float*)d_in[18];
    const float* bp2     = (const float*)d_in[19];
    const float* Wf1     = (const float*)d_in[20];
    const float* bf1     = (const float*)d_in[21];
    const float* Wf2     = (const float*)d_in[22];
    const float* bf2     = (const float*)d_in[23];
    const float* Wf3     = (const float*)d_in[24];
    const float* bf3     = (const float*)d_in[25];
    float* out = (float*)d_out;
    (void)in_sizes; (void)n_in; (void)out_size; (void)ws_size;

    // ---- workspace layout (MB offsets, liveness-reused; peak < 896 MB) ----
    const unsigned long long MBy = 1048576ULL;
    char* ws = (char*)d_ws;
    f16*  xT     = (f16*)(ws + 0 * MBy);       // [B][C][T]   ph1-3
    f16*  Wt     = (f16*)(ws + 128 * MBy);     // [D][T]/[D][D] transposed W slot
    float* sens_f= (float*)(ws + 256 * MBy);   // [B][C][D] fp32  ph3-4
    f16*  sens   = (f16*)(ws + 0 * MBy);       // [B][C][D]   ph4-V (xT dead)
    f16*  Qp     = (f16*)(ws + 256 * MBy);     // [B][C][D]   ph5-S2 (sens_f dead)
    f16*  Kp     = (f16*)(ws + 384 * MBy);     // [B][C][D]   ph6-S1
    f16*  S1T    = (f16*)(ws + 512 * MBy);     // [B][C][C]^T ph7-S3
    f16*  bas    = (f16*)(ws + 576 * MBy);     // [C][D]      ph8
    f16*  S2T    = (f16*)(ws + 640 * MBy);     // [B][C][C]^T ph8-S3
    float* S3    = (float*)(ws + 704 * MBy);   // [B][C][C] fp32  ph9-10
    f16*  attn   = (f16*)(ws + 256 * MBy);     // [B][C][C]   ph10-fused (Q dead)
    f16*  VT     = (f16*)(ws + 384 * MBy);     // [B][D][C]   ph11-fused (K dead)
    float* fusedp= (float*)(ws + 512 * MBy);   // [B][C][D] fp32 (S1T/S2T/S3 dead)
    float* hpool = (float*)(ws + 800 * MBy);
    float* pscr  = (float*)(ws + 820 * MBy);
    float* pooled= (float*)(ws + 822 * MBy);
    float* h1    = (float*)(ws + 824 * MBy);
    float* h2    = (float*)(ws + 828 * MBy);

    const long long CD  = (long long)CC_ * DD;   // 524288
    const long long CCs = (long long)CC_ * CC_;  // 262144
    const long long DC  = (long long)DD * CC_;
    const dim3 blk(256);
    const dim3 blkG(512);

    // 1. x_enc [B][T][C] -> xT fp16 [B][C][T]
    transpose_h_kernel<<<dim3(CC_ / 32, TT / 32, BB), blk, 0, stream>>>(
        x_enc, xT, TT, CC_, (long long)TT * CC_, (long long)CC_ * TT);
    // 2. W_emb [T][D] -> W_embT fp16 [D][T]
    transpose_h_kernel<<<dim3(DD / 32, TT / 32, 1), blk, 0, stream>>>(
        W_emb, Wt, TT, DD, 0, 0);
    // 3. sensor = xT @ W_embT^T + b_emb   (fp32 out)
    mfma_gemm<0><<<dim3(DD / 256, CC_ / 256, BB), blkG, 0, stream>>>(
        xT, Wt, b_emb, nullptr, sens_f,
        CC_, DD, TT, TT, TT, (long long)CC_ * TT, 0, CD, 1.0f);
    // 4. LayerNorm(sensor) -> fp16
    layernorm_h_kernel<<<BB * CC_, blk, 0, stream>>>(sens_f, g_s, b_s, sens);
    // 5. Wq -> WqT fp16; Q = sensor @ Wq + bq -> fp16
    transpose_h_kernel<<<dim3(DD / 32, DD / 32, 1), blk, 0, stream>>>(
        Wq, Wt, DD, DD, 0, 0);
    mfma_gemm<1><<<dim3(DD / 256, (BB * CC_) / 256, 1), blkG, 0, stream>>>(
        sens, Wt, bq, nullptr, Qp,
        BB * CC_, DD, DD, DD, DD, 0, 0, 0, 1.0f);
    // 6. Wk -> WkT fp16; K = sensor @ Wk + bk -> fp16
    transpose_h_kernel<<<dim3(DD / 32, DD / 32, 1), blk, 0, stream>>>(
        Wk, Wt, DD, DD, 0, 0);
    mfma_gemm<1><<<dim3(DD / 256, (BB * CC_) / 256, 1), blkG, 0, stream>>>(
        sens, Wt, bk, nullptr, Kp,
        BB * CC_, DD, DD, DD, DD, 0, 0, 0, 1.0f);
    // 7. S1T = (Q K^T / 32 + age)^T  fp16  (transposed epilogue)
    mfma_gemm<2><<<dim3(CC_ / 256, CC_ / 256, BB), blkG, 0, stream>>>(
        Qp, Kp, nullptr, age_sc, S1T,
        CC_, CC_, DD, DD, DD, CD, CD, CCs, INV_SQRT_D);
    // 8. basis -> fp16; S2T = (Q basis^T / 32)^T fp16
    cvt_h_kernel<<<(CC_ * DD) / 1024, blk, 0, stream>>>(
        basis, bas, (long long)CC_ * DD);
    mfma_gemm<2><<<dim3(CC_ / 256, CC_ / 256, BB), blkG, 0, stream>>>(
        Qp, bas, nullptr, nullptr, S2T,
        CC_, CC_, DD, DD, DD, CD, 0, CCs, INV_SQRT_D);
    // 9. S3[n,k] = sum_j S2T[n,j]*S1T[k,j]   (fp32 out)
    mfma_gemm<0><<<dim3(CC_ / 256, CC_ / 256, BB), blkG, 0, stream>>>(
        S2T, S1T, nullptr, nullptr, S3,
        CC_, CC_, CC_, CC_, CC_, CCs, CCs, CCs, 1.0f);
    // 10. attn = softmax(S3) -> fp16
    softmax512_h_kernel<<<BB * CC_, blk, 0, stream>>>(S3, attn);
    // 11. Wv -> WvT fp16; VT = (sensor @ Wv + bv)^T fp16  [B][D][C]
    transpose_h_kernel<<<dim3(DD / 32, DD / 32, 1), blk, 0, stream>>>(
        Wv, Wt, DD, DD, 0, 0);
    mfma_gemm<2><<<dim3(DD / 256, CC_ / 256, BB), blkG, 0, stream>>>(
        sens, Wt, bv, nullptr, VT,
        CC_, DD, DD, DD, DD, CD, 0, DC, 1.0f);
    // 12. fused[n,d] = sum_m attn[n,m] * VT[d,m] / 32   (fp32 out)
    mfma_gemm<0><<<dim3(DD / 256, CC_ / 256, BB), blkG, 0, stream>>>(
        attn, VT, nullptr, nullptr, fusedp,
        CC_, DD, CC_, CC_, CC_, CCs, DC, CD, INV_SQRT_D);
    // 13. LayerNorm(fused) in place (fp32)
    layernorm_kernel<<<BB * CC_, blk, 0, stream>>>(fusedp, g_f, b_f);
    // 14. hpool = gelu(fused @ Wp1 + bp1)  (fp32 path)
    gemm_kernel<0, 0, 2><<<dim3(HH / 64, (BB * CC_) / 64, 1), blk, 0, stream>>>(
        fusedp, Wp1, bp1, nullptr, hpool, BB * CC_, HH, DD, 0, 0, 0, 1.0f);
    // 15. pool scores + softmax over C
    pool_score_kernel<<<(BB * CC_) / 4, blk, 0, stream>>>(hpool, Wp2, bp2, pscr);
    softmax512_kernel<<<BB, blk, 0, stream>>>(pscr);
    // 16. pooled
    pooled_kernel<<<dim3(DD / 256, BB), blk, 0, stream>>>(fusedp, pscr, pooled);
    // 17. fc head
    gemm_kernel<0, 0, 1><<<dim3(DF_ / 64, BB / 64, 1), blk, 0, stream>>>(
        pooled, Wf1, bf1, nullptr, h1, BB, DF_, DD, 0, 0, 0, 1.0f);
    gemm_kernel<0, 0, 0><<<dim3(DF_ / 64, BB / 64, 1), blk, 0, stream>>>(
        h1, Wf2, bf2, nullptr, h2, BB, DF_, DF_, 0, 0, 0, 1.0f);
    rul_kernel<<<BB, blk, 0, stream>>>(h2, Wf3, bf3, out);
}